// Round 3
// baseline (66780.835 us; speedup 1.0000x reference)
//
#include <hip/hip_runtime.h>
#include <hip/hip_bf16.h>
#include <hip/hip_cooperative_groups.h>

namespace cg = cooperative_groups;

using bf16 = __hip_bfloat16;
typedef __attribute__((ext_vector_type(8))) short short8;
typedef __attribute__((ext_vector_type(4))) float floatx4;

static constexpr int B_ = 256;   // batch
static constexpr int T_ = 128;   // time steps
static constexpr int GRID = 512; // 2 blocks/CU, cooperative

__device__ __forceinline__ float bf2f(bf16 v) { return __bfloat162float(v); }
__device__ __forceinline__ bf16  f2bf(float v) { return __float2bfloat16(v); }

enum { MG = 0, MC = 1, MD = 2 };

struct Params {
    const bf16* emb;        // [T][B][32] bf16
    const int*  lens;
    const bf16* kgT[3];     // [2*out][Kt] bf16 (transposed)
    const bf16* kcT[3];     // [out][Kt]
    const float* gb[3];     // fp32 biases (read directly)
    const float* cb[3];
    float* hf[3];           // fp32 running h
    bf16*  hb[3];           // bf16 h (GEMM input)
    bf16*  rh[3];           // bf16 r*h
    float* zb[3];           // fp32 z gate
    const bf16* dwT;        // [512][3584]
    const float* db;
    float* y;               // [256][512] fp32
};

// ---- fp32 [K][N] -> bf16 [N][K] tiled transpose (K,N multiples of 32) ----
__global__ __launch_bounds__(256) void tpose_k(const float* __restrict__ src,
                                               bf16* __restrict__ dst,
                                               int K, int N)
{
    __shared__ float tile[32][33];
    const int kb = blockIdx.x * 32, nb = blockIdx.y * 32;
    const int tx = threadIdx.x & 31, ty = threadIdx.x >> 5;  // 32x8
    for (int i = ty; i < 32; i += 8)
        tile[i][tx] = src[(size_t)(kb + i) * N + nb + tx];
    __syncthreads();
    for (int i = ty; i < 32; i += 8)
        dst[(size_t)(nb + i) * K + kb + tx] = f2bf(tile[tx][i]);
}

// ---- emb_all[t][b][0:32] = bf16(emb_table[seq[b][t]]) ----
__global__ __launch_bounds__(256) void embed_k(const int* __restrict__ seq,
                                               const float* __restrict__ tab,
                                               bf16* __restrict__ emb_all)
{
    int c = blockIdx.x * 256 + threadIdx.x;  // T_*B_*4 chunks of 8 elems
    int t = c >> 10;
    int r = c & 1023;
    int b = r >> 2, i = r & 3;
    int tok = seq[b * T_ + t];
    const float* s = tab + (size_t)tok * 32 + i * 8;
    bf16 tmp[8];
#pragma unroll
    for (int j = 0; j < 8; ++j) tmp[j] = f2bf(s[j]);
    *(uint4*)(emb_all + ((size_t)t * B_ + b) * 32 + i * 8) = *(uint4*)tmp;
}

// One 32x64 output tile (if v < 8*nt). A = [s0|s1|s2] row-major bf16 segments
// (segment ends e0<=e1<=e2=Ktot, all multiples of 32). BT = bf16 [N][Ktot].
__device__ void gemm_phase(int mode,
    const bf16* s0, int ld0, int e0,
    const bf16* s1, int ld1, int e1,
    const bf16* s2, int ld2, int e2,
    const bf16* __restrict__ BT, const float* __restrict__ bias, int out,
    float* hf, bf16* hb, bf16* rh, float* zb,
    const int* lens, int t, float* y,
    int nt, int v, bf16* As, bf16* Bs)
{
    if (v >= 8 * nt) return;
    const int tid  = threadIdx.x;
    const int bm   = (v & 7) * 32;
    const int bn   = (v >> 3) * 64;
    const int lane = tid & 63, wv = tid >> 6;
    const int wm   = (wv >> 1) * 16, wn = (wv & 1) * 32;
    const int quad = lane >> 4, l16 = lane & 15;
    const int srow = tid >> 2, skc = (tid & 3) * 8;  // 64 rows x 4 chunks

    floatx4 acc0 = {0.f, 0.f, 0.f, 0.f}, acc1 = {0.f, 0.f, 0.f, 0.f};

    const bf16* btp = BT + (size_t)(bn + srow) * e2 + skc;

    for (int k0 = 0; k0 < e2; k0 += 32) {
        // A tile: 32 rows x 32 k (threads 0..127), 16B ld / 16B LDS store
        if (tid < 128) {
            const bf16* sp; int ld, kb;
            if (k0 < e0)      { sp = s0; ld = ld0; kb = k0; }
            else if (k0 < e1) { sp = s1; ld = ld1; kb = k0 - e0; }
            else              { sp = s2; ld = ld2; kb = k0 - e1; }
            uint4 av = *(const uint4*)(sp + (size_t)(bm + srow) * ld + kb + skc);
            *(uint4*)&As[srow * 32 + skc] = av;
        }
        // B tile: 64 n-rows x 32 k, contiguous (pre-transposed)
        uint4 bv = *(const uint4*)(btp + k0);
        *(uint4*)&Bs[srow * 32 + skc] = bv;
        __syncthreads();

        short8 af  = *(const short8*)&As[(wm + l16) * 32 + quad * 8];
        short8 bw0 = *(const short8*)&Bs[(wn + l16) * 32 + quad * 8];
        short8 bw1 = *(const short8*)&Bs[(wn + 16 + l16) * 32 + quad * 8];
        acc0 = __builtin_amdgcn_mfma_f32_16x16x32_bf16(af, bw0, acc0, 0, 0, 0);
        acc1 = __builtin_amdgcn_mfma_f32_16x16x32_bf16(af, bw1, acc1, 0, 0, 0);
        __syncthreads();
    }

    // epilogue
#pragma unroll
    for (int nf = 0; nf < 2; ++nf) {
        floatx4 a = nf ? acc1 : acc0;
        const int col = bn + wn + nf * 16 + l16;
#pragma unroll
        for (int r = 0; r < 4; ++r) {
            const int row = bm + wm + quad * 4 + r;
            float vv = a[r] + bias[col];
            if (mode == MG) {
                float s = 1.f / (1.f + __expf(-vv));
                if (col < out) {
                    size_t idx = (size_t)row * out + col;
                    rh[idx] = f2bf(s * hf[idx]);
                } else {
                    zb[(size_t)row * out + (col - out)] = s;
                }
            } else if (mode == MC) {
                float c = tanhf(vv);
                size_t idx = (size_t)row * out + col;
                float zv = zb[idx], ho = hf[idx];
                float hn = (t < lens[row]) ? (zv * ho + (1.f - zv) * c) : ho;
                hf[idx] = hn;
                hb[idx] = f2bf(hn);
            } else {
                y[(size_t)row * 512 + col] = tanhf(vv);
            }
        }
    }
}

__global__ __launch_bounds__(256, 2) void gru_k(Params p)
{
    cg::grid_group grid = cg::this_grid();
    __shared__ __align__(16) bf16 As[32 * 32];
    __shared__ __align__(16) bf16 Bs[64 * 32];

    const int bid = blockIdx.x;
    const int v = (bid & 7) * (GRID / 8) + (bid >> 3);  // XCD-contiguous n-ranges
    const int outs[3] = {512, 1024, 2048};

    for (int t = 0; t < T_; ++t) {
        const bf16* x = p.emb + (size_t)t * B_ * 32;
        int ldx = 32, kx = 32;
        for (int l = 0; l < 3; ++l) {
            const int out = outs[l];
            const int Kt = kx + out;
            // gates: sigmoid([x|h] @ KgT^T + gb) -> rh, zb
            gemm_phase(MG, x, ldx, kx, p.hb[l], out, Kt, nullptr, 0, Kt,
                       p.kgT[l], p.gb[l], out, p.hf[l], nullptr, p.rh[l], p.zb[l],
                       nullptr, 0, nullptr, (2 * out) / 64, v, As, Bs);
            grid.sync();
            // cand: tanh([x|rh] @ KcT^T + cb) -> h update
            gemm_phase(MC, x, ldx, kx, p.rh[l], out, Kt, nullptr, 0, Kt,
                       p.kcT[l], p.cb[l], out, p.hf[l], p.hb[l], nullptr, p.zb[l],
                       p.lens, t, nullptr, out / 64, v, As, Bs);
            grid.sync();
            x = p.hb[l]; ldx = out; kx = out;
        }
    }
    // dense: y = tanh([h0|h1|h2] @ dwT^T + db)
    gemm_phase(MD, p.hb[0], 512, 512, p.hb[1], 1024, 1536, p.hb[2], 2048, 3584,
               p.dwT, p.db, 512, nullptr, nullptr, nullptr, nullptr,
               nullptr, 0, p.y, 512 / 64, v, As, Bs);
}

extern "C" void kernel_launch(void* const* d_in, const int* in_sizes, int n_in,
                              void* d_out, int out_size, void* d_ws, size_t ws_size,
                              hipStream_t stream)
{
    const int*   seq  = (const int*)d_in[0];
    const int*   lens = (const int*)d_in[1];
    const float* tab  = (const float*)d_in[2];
    const float* gkF[3] = {(const float*)d_in[3], (const float*)d_in[7], (const float*)d_in[11]};
    const float* gbF[3] = {(const float*)d_in[4], (const float*)d_in[8], (const float*)d_in[12]};
    const float* ckF[3] = {(const float*)d_in[5], (const float*)d_in[9], (const float*)d_in[13]};
    const float* cbF[3] = {(const float*)d_in[6], (const float*)d_in[10], (const float*)d_in[14]};
    const float* dwF = (const float*)d_in[15];
    const float* dbF = (const float*)d_in[16];

    const int outs[3] = {512, 1024, 2048};
    const int ins[3]  = {32, 512, 1024};

    char* w = (char*)d_ws;
    auto alloc = [&](size_t bytes) -> void* {
        void* pp = (void*)w;
        w += (bytes + 255) & ~(size_t)255;
        return pp;
    };

    Params p;
    p.lens = lens;
    p.db   = dbF;
    p.y    = (float*)d_out;

    bf16* kgT[3]; bf16* kcT[3];
    for (int l = 0; l < 3; ++l) {
        const int Kt = ins[l] + outs[l];
        kgT[l] = (bf16*)alloc((size_t)2 * outs[l] * Kt * sizeof(bf16));
        kcT[l] = (bf16*)alloc((size_t)outs[l] * Kt * sizeof(bf16));
        p.kgT[l] = kgT[l];
        p.kcT[l] = kcT[l];
        p.gb[l] = gbF[l];
        p.cb[l] = cbF[l];
    }
    bf16* dwT = (bf16*)alloc((size_t)512 * 3584 * sizeof(bf16));
    p.dwT = dwT;

    bf16* emb_all = (bf16*)alloc((size_t)T_ * B_ * 32 * sizeof(bf16));
    p.emb = emb_all;

    for (int l = 0; l < 3; ++l) {
        p.hf[l] = (float*)alloc((size_t)B_ * outs[l] * sizeof(float));
        p.hb[l] = (bf16*)alloc((size_t)B_ * outs[l] * sizeof(bf16));
        p.rh[l] = (bf16*)alloc((size_t)B_ * outs[l] * sizeof(bf16));
        p.zb[l] = (float*)alloc((size_t)B_ * outs[l] * sizeof(float));
    }

    // weight transposes (fp32 -> bf16 [N][K])
    for (int l = 0; l < 3; ++l) {
        const int Kt = ins[l] + outs[l];
        tpose_k<<<dim3(Kt / 32, 2 * outs[l] / 32), 256, 0, stream>>>(gkF[l], kgT[l], Kt, 2 * outs[l]);
        tpose_k<<<dim3(Kt / 32, outs[l] / 32), 256, 0, stream>>>(ckF[l], kcT[l], Kt, outs[l]);
    }
    tpose_k<<<dim3(3584 / 32, 512 / 32), 256, 0, stream>>>(dwF, dwT, 3584, 512);

    // zero initial states
    for (int l = 0; l < 3; ++l) {
        hipMemsetAsync(p.hf[l], 0, (size_t)B_ * outs[l] * sizeof(float), stream);
        hipMemsetAsync(p.hb[l], 0, (size_t)B_ * outs[l] * sizeof(bf16), stream);
    }

    embed_k<<<T_ * B_ * 4 / 256, 256, 0, stream>>>(seq, tab, emb_all);

    void* args[] = {&p};
    hipLaunchCooperativeKernel(reinterpret_cast<void*>(gru_k),
                               dim3(GRID), dim3(256), args, 0, stream);
}